// Round 8
// baseline (193.020 us; speedup 1.0000x reference)
//
#include <hip/hip_runtime.h>

#define NROWS 8192
#define DDIM  1024

typedef short  bf16x8 __attribute__((ext_vector_type(8)));  // 8 bf16 in 4 VGPRs
typedef float  f32x4  __attribute__((ext_vector_type(4)));
typedef unsigned short ushort_t;

// ---- round-to-nearest-even fp32 -> bf16 (bit pattern in ushort) ----
__device__ __forceinline__ ushort_t f2bf(float f) {
    union { float f; unsigned u; } v; v.f = f;
    unsigned r = v.u + 0x7fffu + ((v.u >> 16) & 1u);
    return (ushort_t)(r >> 16);
}

// async global->LDS, 16B per lane, linear LDS dest (wave-uniform base + lane*16)
#define GLD(gp, lp)                                                        \
    __builtin_amdgcn_global_load_lds(                                      \
        (const __attribute__((address_space(1))) void*)(gp),               \
        (__attribute__((address_space(3))) void*)(lp), 16, 0, 0)

// ============================================================================
// Kernel 1: row L2-normalize fp32 -> bf16. One WAVE per row (no block sync),
// 4 rows/block. Also zeroes top/bot (and out).
// ============================================================================
__global__ __launch_bounds__(256) void snnl_normalize(
    const float* __restrict__ x, ushort_t* __restrict__ xn,
    float* __restrict__ top, float* __restrict__ bot, float* __restrict__ out)
{
    const int tid  = (int)threadIdx.x;
    const int lane = tid & 63;
    const int row  = (int)blockIdx.x * 4 + (tid >> 6);
    if (lane == 0) { top[row] = 0.0f; bot[row] = 0.0f; }
    if (row == 0 && lane == 0) out[0] = 0.0f;

    const float4* xr = (const float4*)(x + (size_t)row * DDIM);
    float4 v[4];
#pragma unroll
    for (int st = 0; st < 4; ++st) v[st] = xr[st * 64 + lane];
    float ss = 0.0f;
#pragma unroll
    for (int st = 0; st < 4; ++st)
        ss += v[st].x * v[st].x + v[st].y * v[st].y
            + v[st].z * v[st].z + v[st].w * v[st].w;
#pragma unroll
    for (int m = 32; m >= 1; m >>= 1) ss += __shfl_xor(ss, m);
    const float inv = 1.0f / fmaxf(sqrtf(ss), 1e-8f);   // COS_EPS clamp
    ushort4* xo = (ushort4*)(xn + (size_t)row * DDIM);
#pragma unroll
    for (int st = 0; st < 4; ++st) {
        ushort4 o;
        o.x = f2bf(v[st].x * inv);
        o.y = f2bf(v[st].y * inv);
        o.z = f2bf(v[st].z * inv);
        o.w = f2bf(v[st].w * inv);
        xo[st * 64 + lane] = o;
    }
}

// ============================================================================
// Kernel 2: fused sim-GEMM + exp + masked row/col sums, upper triangle.
//  256(i) x 128(j) block tile, 512 threads = 8 waves (4x2), wave = 64x64.
//  B-tile shared across 2 stacked 128-row subtiles -> staging/tile 384KB
//  (was 512KB) and 64 MFMAs per barrier drain (was 32) — attacks the
//  measured L3-latency staging stall (R7: MfmaUtil 26.5%).
//  Block (bi2,bj) exists iff bj >= 2*bi2 (1056 blocks). Subtile s in {0,1}
//  has tile-row bi_s = 2*bi2+s: valid (contributes rows) iff bi_s <= bj,
//  strict (also contributes transposed col-sums) iff bi_s < bj. sim is
//  bit-exact symmetric (same products, same k-order).
//  XCD-coherent superblock schedule (R7-verified): superblock = 4x8 blocks
//  (1024x1024 out, 4MB = one XCD L2), Q-major triangle order, exact
//  1056 = 8*132 split via bid%8.
//  LDS XOR-swizzled (byte ^= (row&7)<<4) via pre-swizzled global source
//  (global_load_lds writes linearly) + swizzled ds_read -> conflict-free b128.
// ============================================================================
__global__ __launch_bounds__(512, 4) void snnl_main(
    const ushort_t* __restrict__ xn, const int* __restrict__ y,
    const float* __restrict__ T,
    float* __restrict__ top, float* __restrict__ bot)
{
    // ---- XCD-coherent global order ----
    const int bid = (int)blockIdx.x;
    int rem = (bid & 7) * 132 + (bid >> 3);      // global block index [0,1056)
    int P = 0, Q = 0;
    {
        bool done = false;
        for (int qq = 0; qq < 8 && !done; ++qq) {
            for (int pp = 0; pp <= qq; ++pp) {
                const int c = (pp == qq) ? 20 : 32;
                if (rem < c) { P = pp; Q = qq; done = true; break; }
                rem -= c;
            }
        }
    }
    int l, m;                                    // bi2 local [0,4), bj local [0,8)
    if (P == Q) {                                // diag superblock: m >= 2l
        if      (rem < 8)  { l = 0; m = rem; }
        else if (rem < 14) { l = 1; m = rem - 8 + 2; }
        else if (rem < 18) { l = 2; m = rem - 14 + 4; }
        else               { l = 3; m = rem - 18 + 6; }
    } else {                                     // full: B-tile-major
        l = rem & 3; m = rem >> 2;
    }
    const int bi2 = P * 4 + l;                   // 256-row panel [0,32)
    const int bj  = Q * 8 + m;                   // 128-col tile  [0,64)

    __shared__ char smem[49152];                 // A 32KB | B 16KB
    __shared__ int  yrow_s[256];
    __shared__ int  ycol_s[128];

    const int tid  = (int)threadIdx.x;
    const int lane = tid & 63;
    const int w    = tid >> 6;
    const int wr   = w >> 1;              // wave row (0..3) -> 64 output rows
    const int wc   = w & 1;               // wave col (0..1) -> 64 output cols
    const int i0   = bi2 * 256;
    const int j0   = bj * 128;

    // per-wave subtile masks
    const int  s      = wr >> 1;                 // subtile 0 or 1
    const int  bi_s   = 2 * bi2 + s;
    const bool valid  = (bi_s <= bj);            // contributes row sums
    const bool strict = (bi_s <  bj);            // contributes col sums

    if (tid < 256)       yrow_s[tid] = y[i0 + tid];
    else if (tid < 384)  ycol_s[tid - 256] = y[j0 + tid - 256];
    // first K-loop __syncthreads() covers these before any use

    const float invT = 1.0f / T[0];

    // --- staging constants: thread t writes LDS bytes [q*8192 + t*16, +16) ---
    // LDS linear offset o: row = o>>7, col byte = o&127.
    // Swizzle (involution): stored col = col ^ ((row&7)<<4).
    const int  rr  = tid >> 3;                               // tile row % 64
    const int  scb = (((tid & 7) ^ (rr & 7)) << 4);          // source col byte
    const char* const xb = (const char*)xn;

    // --- fragment-read constants (read side applies the same XOR) ---
    const int c0 = (((lane >> 4) << 4)) ^ ((lane & 7) << 4);
    int arow[4], brow[4];
#pragma unroll
    for (int mi = 0; mi < 4; ++mi) arow[mi] = (wr * 64 + mi * 16 + (lane & 15)) * 128;
#pragma unroll
    for (int ni = 0; ni < 4; ++ni) brow[ni] = 32768 + (wc * 64 + ni * 16 + (lane & 15)) * 128;

    const f32x4 zero4 = {0.0f, 0.0f, 0.0f, 0.0f};
    f32x4 acc[4][4];
#pragma unroll
    for (int mi = 0; mi < 4; ++mi)
#pragma unroll
        for (int ni = 0; ni < 4; ++ni) acc[mi][ni] = zero4;

    for (int kt = 0; kt < 16; ++kt) {
        const size_t kb = ((size_t)kt << 7) + (size_t)scb;
#pragma unroll
        for (int qq = 0; qq < 4; ++qq)           // A: 256 rows
            GLD(xb + (((size_t)(i0 + qq * 64 + rr)) << 11) + kb,
                smem + (qq << 13) + (tid << 4));
#pragma unroll
        for (int qq = 0; qq < 2; ++qq)           // B: 128 rows
            GLD(xb + (((size_t)(j0 + qq * 64 + rr)) << 11) + kb,
                smem + 32768 + (qq << 13) + (tid << 4));
        __syncthreads();   // compiler drains vmcnt before s_barrier

#pragma unroll
        for (int ks = 0; ks < 2; ++ks) {
            const int cks = c0 ^ (ks << 6);
            bf16x8 af[4], bfr[4];
#pragma unroll
            for (int mi = 0; mi < 4; ++mi)
                af[mi] = *(const bf16x8*)(smem + arow[mi] + cks);
#pragma unroll
            for (int ni = 0; ni < 4; ++ni)
                bfr[ni] = *(const bf16x8*)(smem + brow[ni] + cks);
#pragma unroll
            for (int mi = 0; mi < 4; ++mi)
#pragma unroll
                for (int ni = 0; ni < 4; ++ni)
                    acc[mi][ni] = __builtin_amdgcn_mfma_f32_16x16x32_bf16(
                        af[mi], bfr[ni], acc[mi][ni], 0, 0, 0);
        }
        __syncthreads();
    }

    // ---- fused epilogue: f = exp((sim-1)/T), masked row AND col sums ----
    int yjv[4], jgv[4];
#pragma unroll
    for (int ni = 0; ni < 4; ++ni) {
        const int jloc = wc * 64 + ni * 16 + (lane & 15);
        yjv[ni] = ycol_s[jloc];
        jgv[ni] = j0 + jloc;
    }
    float ct[4], cb[4];                 // column accumulators (per ni)
#pragma unroll
    for (int ni = 0; ni < 4; ++ni) { ct[ni] = 0.0f; cb[ni] = 0.0f; }

    if (valid) {
#pragma unroll
        for (int mi = 0; mi < 4; ++mi) {
#pragma unroll
            for (int r = 0; r < 4; ++r) {
                const int il = wr * 64 + mi * 16 + ((lane >> 4) << 2) + r;
                const int ig = i0 + il;
                const int yi = yrow_s[il];
                float ba = 0.0f, ta = 0.0f;
#pragma unroll
                for (int ni = 0; ni < 4; ++ni) {
                    const float fv = __expf((acc[mi][ni][r] - 1.0f) * invT);
                    const bool  sm = (yi == yjv[ni]);
                    const float bv = (ig != jgv[ni]) ? fv : 0.0f;  // off-diag
                    const float tv = sm ? bv : 0.0f;               // same-label
                    ba += bv;  ta += tv;
                    cb[ni] += bv;  ct[ni] += tv;                   // mirror tile
                }
                // row reduce across the 16 lanes sharing this row, one atomic
                ta += __shfl_xor(ta, 1); ta += __shfl_xor(ta, 2);
                ta += __shfl_xor(ta, 4); ta += __shfl_xor(ta, 8);
                ba += __shfl_xor(ba, 1); ba += __shfl_xor(ba, 2);
                ba += __shfl_xor(ba, 4); ba += __shfl_xor(ba, 8);
                if ((lane & 15) == 0) {
                    atomicAdd(&top[ig], ta);
                    atomicAdd(&bot[ig], ba);
                }
            }
        }
    }

    if (strict) {
        // col reduce: col = lane&15 fixed, sum the 4 lane-quarters
#pragma unroll
        for (int ni = 0; ni < 4; ++ni) {
            float tv = ct[ni], bv = cb[ni];
            tv += __shfl_xor(tv, 16); tv += __shfl_xor(tv, 32);
            bv += __shfl_xor(bv, 16); bv += __shfl_xor(bv, 32);
            if (lane < 16) {
                atomicAdd(&top[jgv[ni]], tv);
                atomicAdd(&bot[jgv[ni]], bv);
            }
        }
    }
}

// ============================================================================
// Kernel 3: loss = -mean(log((top+1e-9)/bot)); out pre-zeroed by normalize.
// ============================================================================
__global__ __launch_bounds__(256) void snnl_loss(
    const float* __restrict__ top, const float* __restrict__ bot,
    float* __restrict__ out)
{
    const int tid = (int)threadIdx.x;
    const int i   = (int)blockIdx.x * 256 + tid;
    float s = __logf((top[i] + 1e-9f) / bot[i]);
#pragma unroll
    for (int m = 32; m >= 1; m >>= 1) s += __shfl_xor(s, m);
    __shared__ float w4[4];
    if ((tid & 63) == 0) w4[tid >> 6] = s;
    __syncthreads();
    if (tid == 0)
        atomicAdd(out, -(w4[0] + w4[1] + w4[2] + w4[3]) * (1.0f / (float)NROWS));
}

// ============================================================================
extern "C" void kernel_launch(void* const* d_in, const int* in_sizes, int n_in,
                              void* d_out, int out_size, void* d_ws, size_t ws_size,
                              hipStream_t stream)
{
    const float* x = (const float*)d_in[0];
    const int*   y = (const int*)d_in[1];
    const float* T = (const float*)d_in[2];
    float* out = (float*)d_out;

    char* ws = (char*)d_ws;
    ushort_t* xn  = (ushort_t*)ws;                              // 16 MiB bf16 Xn
    float*    top = (float*)(ws + (size_t)16 * 1024 * 1024);    // 32 KiB
    float*    bot = top + NROWS;                                // 32 KiB

    snnl_normalize<<<NROWS / 4, 256, 0, stream>>>(x, xn, top, bot, out);
    snnl_main<<<1056, 512, 0, stream>>>(xn, y, T, top, bot);
    snnl_loss<<<NROWS / 256, 256, 0, stream>>>(top, bot, out);
}

// Round 10
// 189.564 us; speedup vs baseline: 1.0182x; 1.0182x over previous
//
#include <hip/hip_runtime.h>

#define NROWS 8192
#define DDIM  1024

typedef short  bf16x8 __attribute__((ext_vector_type(8)));  // 8 bf16 in 4 VGPRs
typedef float  f32x4  __attribute__((ext_vector_type(4)));
typedef unsigned short ushort_t;

// ---- round-to-nearest-even fp32 -> bf16 (bit pattern in ushort) ----
__device__ __forceinline__ ushort_t f2bf(float f) {
    union { float f; unsigned u; } v; v.f = f;
    unsigned r = v.u + 0x7fffu + ((v.u >> 16) & 1u);
    return (ushort_t)(r >> 16);
}

// async global->LDS, 16B per lane, linear LDS dest (wave-uniform base + lane*16)
#define GLD(gp, lp)                                                        \
    __builtin_amdgcn_global_load_lds(                                      \
        (const __attribute__((address_space(1))) void*)(gp),               \
        (__attribute__((address_space(3))) void*)(lp), 16, 0, 0)

// ============================================================================
// Kernel 1: row L2-normalize fp32 -> bf16. One WAVE per row (no block sync),
// 4 rows/block. Also zeroes top/bot (and out).
// ============================================================================
__global__ __launch_bounds__(256) void snnl_normalize(
    const float* __restrict__ x, ushort_t* __restrict__ xn,
    float* __restrict__ top, float* __restrict__ bot, float* __restrict__ out)
{
    const int tid  = (int)threadIdx.x;
    const int lane = tid & 63;
    const int row  = (int)blockIdx.x * 4 + (tid >> 6);
    if (lane == 0) { top[row] = 0.0f; bot[row] = 0.0f; }
    if (row == 0 && lane == 0) out[0] = 0.0f;

    const float4* xr = (const float4*)(x + (size_t)row * DDIM);
    float4 v[4];
#pragma unroll
    for (int st = 0; st < 4; ++st) v[st] = xr[st * 64 + lane];
    float ss = 0.0f;
#pragma unroll
    for (int st = 0; st < 4; ++st)
        ss += v[st].x * v[st].x + v[st].y * v[st].y
            + v[st].z * v[st].z + v[st].w * v[st].w;
#pragma unroll
    for (int m = 32; m >= 1; m >>= 1) ss += __shfl_xor(ss, m);
    const float inv = 1.0f / fmaxf(sqrtf(ss), 1e-8f);   // COS_EPS clamp
    ushort4* xo = (ushort4*)(xn + (size_t)row * DDIM);
#pragma unroll
    for (int st = 0; st < 4; ++st) {
        ushort4 o;
        o.x = f2bf(v[st].x * inv);
        o.y = f2bf(v[st].y * inv);
        o.z = f2bf(v[st].z * inv);
        o.w = f2bf(v[st].w * inv);
        xo[st * 64 + lane] = o;
    }
}

// ============================================================================
// Kernel 2: fused sim-GEMM + exp + masked row/col sums, upper triangle.
//  R7-verified structure (128x128 tile, 4 waves 2x2, one tile/block,
//  XCD-coherent 8x8 superblock order, swizzled GLD staging) with ONE change:
//  FORCE 2 blocks/CU (smem padded to 56KB; launch_bounds(256,2)).
//  Rationale (R7/R8 counters): at 4 blocks/CU an XCD hosts ~128 resident
//  tiles = 2-3 superblocks = 8-12MB >> 4MB L2 -> per-tile FETCH 46KB vs
//  R1's 17.6KB; every kt barrier-drain eats an L3-latency load. At 2
//  blocks/CU: 64 resident tiles/XCD = exactly one superblock = 4MB = L2.
//  (R1 ran 2 blocks/CU and holds the best measured per-tile time, 39.6ns.)
//  LDS XOR-swizzled (byte ^= (row&7)<<4) via pre-swizzled global source
//  (global_load_lds writes linearly) + swizzled ds_read -> conflict-free b128.
// ============================================================================
__global__ __launch_bounds__(256, 2) void snnl_main(
    const ushort_t* __restrict__ xn, const int* __restrict__ y,
    const float* __restrict__ T,
    float* __restrict__ top, float* __restrict__ bot)
{
    // ---- tile index from XCD-coherent global order ----
    const int bid = (int)blockIdx.x;
    int rem = (bid & 7) * 260 + (bid >> 3);      // global tile index
    int p = 0, q = 0;
    {
        bool done = false;
        for (int qq = 0; qq < 8 && !done; ++qq) {
            for (int pp = 0; pp <= qq; ++pp) {
                const int c = (pp == qq) ? 36 : 64;
                if (rem < c) { p = pp; q = qq; done = true; break; }
                rem -= c;
            }
        }
    }
    int ti, tj;
    if (p == q) {                                // diag superblock: tri enum
        int t = rem; tj = 7;
        for (int cc = 0; cc < 8; ++cc) {
            if (t <= cc) { tj = cc; break; }
            t -= (cc + 1);
        }
        ti = t;
    } else {                                     // full superblock
        ti = rem & 7; tj = rem >> 3;
    }
    const int bi = p * 8 + ti;
    const int bj = q * 8 + tj;
    const bool strict = (bi < bj);               // off-diagonal tile

    // 56KB: occupancy limiter -> exactly 2 blocks/CU (only first 32KB used
    // for tiles; the pad is intentional, see header comment).
    __shared__ char smem[57344];
    __shared__ int  yrow_s[128];
    __shared__ int  ycol_s[128];

    const int tid  = (int)threadIdx.x;
    const int lane = tid & 63;
    const int w    = tid >> 6;
    const int wr   = w >> 1;              // wave row (0..1) -> 64 output rows
    const int wc   = w & 1;               // wave col (0..1) -> 64 output cols
    const int i0   = bi * 128;
    const int j0   = bj * 128;

    if (tid < 128) yrow_s[tid] = y[i0 + tid];
    else           ycol_s[tid - 128] = y[j0 + tid - 128];
    // first K-loop __syncthreads() covers these before any use

    const float invT = 1.0f / T[0];

    // --- staging constants: thread t writes LDS bytes [q*4096 + t*16, +16) ---
    // LDS linear offset o: row = o>>7, col byte = o&127.
    // Swizzle (involution): stored col = col ^ ((row&7)<<4).
    const int  rr  = tid >> 3;                               // tile row % 32
    const int  scb = (((tid & 7) ^ (rr & 7)) << 4);          // source col byte
    const char* const xb = (const char*)xn;

    // --- fragment-read constants (read side applies the same XOR) ---
    const int c0 = (((lane >> 4) << 4)) ^ ((lane & 7) << 4);
    int arow[4], brow[4];
#pragma unroll
    for (int mi = 0; mi < 4; ++mi) arow[mi] = (wr * 64 + mi * 16 + (lane & 15)) * 128;
#pragma unroll
    for (int ni = 0; ni < 4; ++ni) brow[ni] = 16384 + (wc * 64 + ni * 16 + (lane & 15)) * 128;

    const f32x4 zero4 = {0.0f, 0.0f, 0.0f, 0.0f};
    f32x4 acc[4][4];
#pragma unroll
    for (int mi = 0; mi < 4; ++mi)
#pragma unroll
        for (int ni = 0; ni < 4; ++ni) acc[mi][ni] = zero4;

    for (int kt = 0; kt < 16; ++kt) {
        const size_t kb = ((size_t)kt << 7) + (size_t)scb;
#pragma unroll
        for (int qq = 0; qq < 4; ++qq)
            GLD(xb + (((size_t)(i0 + qq * 32 + rr)) << 11) + kb,
                smem + (qq << 12) + (tid << 4));
#pragma unroll
        for (int qq = 0; qq < 4; ++qq)
            GLD(xb + (((size_t)(j0 + qq * 32 + rr)) << 11) + kb,
                smem + 16384 + (qq << 12) + (tid << 4));
        __syncthreads();   // compiler drains vmcnt before s_barrier

#pragma unroll
        for (int ks = 0; ks < 2; ++ks) {
            const int cks = c0 ^ (ks << 6);
            bf16x8 af[4], bfr[4];
#pragma unroll
            for (int mi = 0; mi < 4; ++mi)
                af[mi] = *(const bf16x8*)(smem + arow[mi] + cks);
#pragma unroll
            for (int ni = 0; ni < 4; ++ni)
                bfr[ni] = *(const bf16x8*)(smem + brow[ni] + cks);
#pragma unroll
            for (int mi = 0; mi < 4; ++mi)
#pragma unroll
                for (int ni = 0; ni < 4; ++ni)
                    acc[mi][ni] = __builtin_amdgcn_mfma_f32_16x16x32_bf16(
                        af[mi], bfr[ni], acc[mi][ni], 0, 0, 0);
        }
        __syncthreads();
    }

    // ---- fused epilogue: f = exp((sim-1)/T), masked row AND col sums ----
    int yjv[4], jgv[4];
#pragma unroll
    for (int ni = 0; ni < 4; ++ni) {
        const int jloc = wc * 64 + ni * 16 + (lane & 15);
        yjv[ni] = ycol_s[jloc];
        jgv[ni] = j0 + jloc;
    }
    float ct[4], cb[4];                 // column accumulators (per ni)
#pragma unroll
    for (int ni = 0; ni < 4; ++ni) { ct[ni] = 0.0f; cb[ni] = 0.0f; }

#pragma unroll
    for (int mi = 0; mi < 4; ++mi) {
#pragma unroll
        for (int r = 0; r < 4; ++r) {
            const int il = wr * 64 + mi * 16 + ((lane >> 4) << 2) + r;
            const int ig = i0 + il;
            const int yi = yrow_s[il];
            float ba = 0.0f, ta = 0.0f;
#pragma unroll
            for (int ni = 0; ni < 4; ++ni) {
                const float fv = __expf((acc[mi][ni][r] - 1.0f) * invT);
                const bool  sm = (yi == yjv[ni]);
                const float bv = (ig != jgv[ni]) ? fv : 0.0f;  // off-diag mask
                const float tv = sm ? bv : 0.0f;               // same-label
                ba += bv;  ta += tv;
                cb[ni] += bv;  ct[ni] += tv;                   // mirror tile
            }
            // row reduce across the 16 lanes sharing this row, one atomic
            ta += __shfl_xor(ta, 1); ta += __shfl_xor(ta, 2);
            ta += __shfl_xor(ta, 4); ta += __shfl_xor(ta, 8);
            ba += __shfl_xor(ba, 1); ba += __shfl_xor(ba, 2);
            ba += __shfl_xor(ba, 4); ba += __shfl_xor(ba, 8);
            if ((lane & 15) == 0) {
                atomicAdd(&top[ig], ta);
                atomicAdd(&bot[ig], ba);
            }
        }
    }

    if (strict) {
        // col reduce: col = lane&15 fixed, sum the 4 lane-quarters
#pragma unroll
        for (int ni = 0; ni < 4; ++ni) {
            float tv = ct[ni], bv = cb[ni];
            tv += __shfl_xor(tv, 16); tv += __shfl_xor(tv, 32);
            bv += __shfl_xor(bv, 16); bv += __shfl_xor(bv, 32);
            if (lane < 16) {
                atomicAdd(&top[jgv[ni]], tv);
                atomicAdd(&bot[jgv[ni]], bv);
            }
        }
    }
}

// ============================================================================
// Kernel 3: loss = -mean(log((top+1e-9)/bot)); out pre-zeroed by normalize.
// ============================================================================
__global__ __launch_bounds__(256) void snnl_loss(
    const float* __restrict__ top, const float* __restrict__ bot,
    float* __restrict__ out)
{
    const int tid = (int)threadIdx.x;
    const int i   = (int)blockIdx.x * 256 + tid;
    float s = __logf((top[i] + 1e-9f) / bot[i]);
#pragma unroll
    for (int m = 32; m >= 1; m >>= 1) s += __shfl_xor(s, m);
    __shared__ float w4[4];
    if ((tid & 63) == 0) w4[tid >> 6] = s;
    __syncthreads();
    if (tid == 0)
        atomicAdd(out, -(w4[0] + w4[1] + w4[2] + w4[3]) * (1.0f / (float)NROWS));
}

// ============================================================================
extern "C" void kernel_launch(void* const* d_in, const int* in_sizes, int n_in,
                              void* d_out, int out_size, void* d_ws, size_t ws_size,
                              hipStream_t stream)
{
    const float* x = (const float*)d_in[0];
    const int*   y = (const int*)d_in[1];
    const float* T = (const float*)d_in[2];
    float* out = (float*)d_out;

    char* ws = (char*)d_ws;
    ushort_t* xn  = (ushort_t*)ws;                              // 16 MiB bf16 Xn
    float*    top = (float*)(ws + (size_t)16 * 1024 * 1024);    // 32 KiB
    float*    bot = top + NROWS;                                // 32 KiB

    snnl_normalize<<<NROWS / 4, 256, 0, stream>>>(x, xn, top, bot, out);
    snnl_main<<<2080, 256, 0, stream>>>(xn, y, T, top, bot);
    snnl_loss<<<NROWS / 256, 256, 0, stream>>>(top, bot, out);
}

// Round 12
// 188.997 us; speedup vs baseline: 1.0213x; 1.0030x over previous
//
#include <hip/hip_runtime.h>

#define NROWS 8192
#define DDIM  1024

typedef short  bf16x8 __attribute__((ext_vector_type(8)));  // 8 bf16 in 4 VGPRs
typedef float  f32x4  __attribute__((ext_vector_type(4)));
typedef unsigned short ushort_t;

// ---- round-to-nearest-even fp32 -> bf16 (bit pattern in ushort) ----
__device__ __forceinline__ ushort_t f2bf(float f) {
    union { float f; unsigned u; } v; v.f = f;
    unsigned r = v.u + 0x7fffu + ((v.u >> 16) & 1u);
    return (ushort_t)(r >> 16);
}

// async global->LDS, 16B per lane, linear LDS dest (wave-uniform base + lane*16)
#define GLD(gp, lp)                                                        \
    __builtin_amdgcn_global_load_lds(                                      \
        (const __attribute__((address_space(1))) void*)(gp),               \
        (__attribute__((address_space(3))) void*)(lp), 16, 0, 0)

// ============================================================================
// Kernel 1: row L2-normalize fp32 -> bf16. One WAVE per row (no block sync),
// 4 rows/block. Also zeroes top/bot (and out).
// ============================================================================
__global__ __launch_bounds__(256) void snnl_normalize(
    const float* __restrict__ x, ushort_t* __restrict__ xn,
    float* __restrict__ top, float* __restrict__ bot, float* __restrict__ out)
{
    const int tid  = (int)threadIdx.x;
    const int lane = tid & 63;
    const int row  = (int)blockIdx.x * 4 + (tid >> 6);
    if (lane == 0) { top[row] = 0.0f; bot[row] = 0.0f; }
    if (row == 0 && lane == 0) out[0] = 0.0f;

    const float4* xr = (const float4*)(x + (size_t)row * DDIM);
    float4 v[4];
#pragma unroll
    for (int st = 0; st < 4; ++st) v[st] = xr[st * 64 + lane];
    float ss = 0.0f;
#pragma unroll
    for (int st = 0; st < 4; ++st)
        ss += v[st].x * v[st].x + v[st].y * v[st].y
            + v[st].z * v[st].z + v[st].w * v[st].w;
#pragma unroll
    for (int m = 32; m >= 1; m >>= 1) ss += __shfl_xor(ss, m);
    const float inv = 1.0f / fmaxf(sqrtf(ss), 1e-8f);   // COS_EPS clamp
    ushort4* xo = (ushort4*)(xn + (size_t)row * DDIM);
#pragma unroll
    for (int st = 0; st < 4; ++st) {
        ushort4 o;
        o.x = f2bf(v[st].x * inv);
        o.y = f2bf(v[st].y * inv);
        o.z = f2bf(v[st].z * inv);
        o.w = f2bf(v[st].w * inv);
        xo[st * 64 + lane] = o;
    }
}

// ============================================================================
// Kernel 2: fused sim-GEMM + exp + masked row/col sums, upper triangle.
//  R7 structure (128x128 tile, 4 waves 2x2, one tile/block, XCD-coherent
//  8x8 superblock order, swizzled GLD staging) + MINIMAL 2-PHASE PIPELINE:
//   - double-buffered LDS (2 x 32KB), ONE __syncthreads() per kt
//   - per kt: ds_read frags of buf[cur]  ->  STAGE(kt+1 -> buf^1)  ->
//             MFMA (lgkm-waited)  ->  __syncthreads (vmcnt0+lgkm0+barrier)
//   Staging latency (L3 ~600cy; R7-R10 counters show every kt drain eats
//   it un-overlapped, 2 barriers/kt) now hides under the 32 MFMAs, and
//   barrier count halves. Race audit: buf^1 writes occur only after the
//   kt-1 barrier (which lgkm-drained all reads of buf^1); buf[cur] reads
//   occur only after the kt-1 barrier (which vmcnt-drained its staging).
//  LDS XOR-swizzled (byte ^= (row&7)<<4) via pre-swizzled global source
//  (global_load_lds writes linearly) + swizzled ds_read -> conflict-free b128.
// ============================================================================
__global__ __launch_bounds__(256, 2) void snnl_main(
    const ushort_t* __restrict__ xn, const int* __restrict__ y,
    const float* __restrict__ T,
    float* __restrict__ top, float* __restrict__ bot)
{
    // ---- tile index from XCD-coherent global order ----
    const int bid = (int)blockIdx.x;
    int rem = (bid & 7) * 260 + (bid >> 3);      // global tile index
    int p = 0, q = 0;
    {
        bool done = false;
        for (int qq = 0; qq < 8 && !done; ++qq) {
            for (int pp = 0; pp <= qq; ++pp) {
                const int c = (pp == qq) ? 36 : 64;
                if (rem < c) { p = pp; q = qq; done = true; break; }
                rem -= c;
            }
        }
    }
    int ti, tj;
    if (p == q) {                                // diag superblock: tri enum
        int t = rem; tj = 7;
        for (int cc = 0; cc < 8; ++cc) {
            if (t <= cc) { tj = cc; break; }
            t -= (cc + 1);
        }
        ti = t;
    } else {                                     // full superblock
        ti = rem & 7; tj = rem >> 3;
    }
    const int bi = p * 8 + ti;
    const int bj = q * 8 + tj;
    const bool strict = (bi < bj);               // off-diagonal tile

    __shared__ char smem[65536];                 // 2 x (A 16KB | B 16KB)
    __shared__ int  yrow_s[128];
    __shared__ int  ycol_s[128];

    const int tid  = (int)threadIdx.x;
    const int lane = tid & 63;
    const int w    = tid >> 6;
    const int wr   = w >> 1;              // wave row (0..1) -> 64 output rows
    const int wc   = w & 1;               // wave col (0..1) -> 64 output cols
    const int i0   = bi * 128;
    const int j0   = bj * 128;

    if (tid < 128) yrow_s[tid] = y[i0 + tid];
    else           ycol_s[tid - 128] = y[j0 + tid - 128];
    // prologue __syncthreads() covers these before any use

    const float invT = 1.0f / T[0];

    // --- staging constants: thread t writes LDS bytes [q*4096 + t*16, +16) ---
    // LDS linear offset o (within buffer): row = o>>7, col byte = o&127.
    // Swizzle (involution): stored col = col ^ ((row&7)<<4).
    const int  rr  = tid >> 3;                               // tile row % 32
    const int  scb = (((tid & 7) ^ (rr & 7)) << 4);          // source col byte
    const char* const xb = (const char*)xn;

#define STAGE(buf, kt)                                                     \
    {                                                                      \
        const size_t kb_ = ((size_t)(kt) << 7) + (size_t)scb;              \
        char* sb_ = smem + ((buf) << 15);                                  \
        _Pragma("unroll")                                                  \
        for (int qq = 0; qq < 4; ++qq)                                     \
            GLD(xb + (((size_t)(i0 + qq * 32 + rr)) << 11) + kb_,          \
                sb_ + (qq << 12) + (tid << 4));                            \
        _Pragma("unroll")                                                  \
        for (int qq = 0; qq < 4; ++qq)                                     \
            GLD(xb + (((size_t)(j0 + qq * 32 + rr)) << 11) + kb_,          \
                sb_ + 16384 + (qq << 12) + (tid << 4));                    \
    }

    // --- fragment-read constants (read side applies the same XOR) ---
    const int c0 = (((lane >> 4) << 4)) ^ ((lane & 7) << 4);
    int arow[4], brow[4];
#pragma unroll
    for (int mi = 0; mi < 4; ++mi) arow[mi] = (wr * 64 + mi * 16 + (lane & 15)) * 128;
#pragma unroll
    for (int ni = 0; ni < 4; ++ni) brow[ni] = 16384 + (wc * 64 + ni * 16 + (lane & 15)) * 128;

    const f32x4 zero4 = {0.0f, 0.0f, 0.0f, 0.0f};
    f32x4 acc[4][4];
#pragma unroll
    for (int mi = 0; mi < 4; ++mi)
#pragma unroll
        for (int ni = 0; ni < 4; ++ni) acc[mi][ni] = zero4;

    // ---- 2-phase pipelined K-loop: one barrier per kt ----
    STAGE(0, 0);
    __syncthreads();                       // buf0 ready; y_s visible

    int cur = 0;
    for (int kt = 0; kt < 16; ++kt) {
        const int sb = cur << 15;
        // (1) read all fragments of current buffer FIRST
        bf16x8 af[2][4], bfr[2][4];
#pragma unroll
        for (int ks = 0; ks < 2; ++ks) {
            const int cks = c0 ^ (ks << 6);
#pragma unroll
            for (int mi = 0; mi < 4; ++mi)
                af[ks][mi] = *(const bf16x8*)(smem + sb + arow[mi] + cks);
#pragma unroll
            for (int ni = 0; ni < 4; ++ni)
                bfr[ks][ni] = *(const bf16x8*)(smem + sb + brow[ni] + cks);
        }
        // (2) issue next tile's staging into the other buffer
        if (kt < 15) STAGE(cur ^ 1, kt + 1);
        // (3) MFMA (compiler inserts lgkm waits for the ds_reads)
#pragma unroll
        for (int ks = 0; ks < 2; ++ks)
#pragma unroll
            for (int mi = 0; mi < 4; ++mi)
#pragma unroll
                for (int ni = 0; ni < 4; ++ni)
                    acc[mi][ni] = __builtin_amdgcn_mfma_f32_16x16x32_bf16(
                        af[ks][mi], bfr[ks][ni], acc[mi][ni], 0, 0, 0);
        // (4) commit point: drains vmcnt(0)+lgkmcnt(0), then barrier
        __syncthreads();
        cur ^= 1;
    }

    // ---- fused epilogue: f = exp((sim-1)/T), masked row AND col sums ----
    int yjv[4], jgv[4];
#pragma unroll
    for (int ni = 0; ni < 4; ++ni) {
        const int jloc = wc * 64 + ni * 16 + (lane & 15);
        yjv[ni] = ycol_s[jloc];
        jgv[ni] = j0 + jloc;
    }
    float ct[4], cb[4];                 // column accumulators (per ni)
#pragma unroll
    for (int ni = 0; ni < 4; ++ni) { ct[ni] = 0.0f; cb[ni] = 0.0f; }

#pragma unroll
    for (int mi = 0; mi < 4; ++mi) {
#pragma unroll
        for (int r = 0; r < 4; ++r) {
            const int il = wr * 64 + mi * 16 + ((lane >> 4) << 2) + r;
            const int ig = i0 + il;
            const int yi = yrow_s[il];
            float ba = 0.0f, ta = 0.0f;
#pragma unroll
            for (int ni = 0; ni < 4; ++ni) {
                const float fv = __expf((acc[mi][ni][r] - 1.0f) * invT);
                const bool  sm = (yi == yjv[ni]);
                const float bv = (ig != jgv[ni]) ? fv : 0.0f;  // off-diag mask
                const float tv = sm ? bv : 0.0f;               // same-label
                ba += bv;  ta += tv;
                cb[ni] += bv;  ct[ni] += tv;                   // mirror tile
            }
            // row reduce across the 16 lanes sharing this row, one atomic
            ta += __shfl_xor(ta, 1); ta += __shfl_xor(ta, 2);
            ta += __shfl_xor(ta, 4); ta += __shfl_xor(ta, 8);
            ba += __shfl_xor(ba, 1); ba += __shfl_xor(ba, 2);
            ba += __shfl_xor(ba, 4); ba += __shfl_xor(ba, 8);
            if ((lane & 15) == 0) {
                atomicAdd(&top[ig], ta);
                atomicAdd(&bot[ig], ba);
            }
        }
    }

    if (strict) {
        // col reduce: col = lane&15 fixed, sum the 4 lane-quarters
#pragma unroll
        for (int ni = 0; ni < 4; ++ni) {
            float tv = ct[ni], bv = cb[ni];
            tv += __shfl_xor(tv, 16); tv += __shfl_xor(tv, 32);
            bv += __shfl_xor(bv, 16); bv += __shfl_xor(bv, 32);
            if (lane < 16) {
                atomicAdd(&top[jgv[ni]], tv);
                atomicAdd(&bot[jgv[ni]], bv);
            }
        }
    }
#undef STAGE
}

// ============================================================================
// Kernel 3: loss = -mean(log((top+1e-9)/bot)); out pre-zeroed by normalize.
// ============================================================================
__global__ __launch_bounds__(256) void snnl_loss(
    const float* __restrict__ top, const float* __restrict__ bot,
    float* __restrict__ out)
{
    const int tid = (int)threadIdx.x;
    const int i   = (int)blockIdx.x * 256 + tid;
    float s = __logf((top[i] + 1e-9f) / bot[i]);
#pragma unroll
    for (int m = 32; m >= 1; m >>= 1) s += __shfl_xor(s, m);
    __shared__ float w4[4];
    if ((tid & 63) == 0) w4[tid >> 6] = s;
    __syncthreads();
    if (tid == 0)
        atomicAdd(out, -(w4[0] + w4[1] + w4[2] + w4[3]) * (1.0f / (float)NROWS));
}

// ============================================================================
extern "C" void kernel_launch(void* const* d_in, const int* in_sizes, int n_in,
                              void* d_out, int out_size, void* d_ws, size_t ws_size,
                              hipStream_t stream)
{
    const float* x = (const float*)d_in[0];
    const int*   y = (const int*)d_in[1];
    const float* T = (const float*)d_in[2];
    float* out = (float*)d_out;

    char* ws = (char*)d_ws;
    ushort_t* xn  = (ushort_t*)ws;                              // 16 MiB bf16 Xn
    float*    top = (float*)(ws + (size_t)16 * 1024 * 1024);    // 32 KiB
    float*    bot = top + NROWS;                                // 32 KiB

    snnl_normalize<<<NROWS / 4, 256, 0, stream>>>(x, xn, top, bot, out);
    snnl_main<<<2080, 256, 0, stream>>>(xn, y, T, top, bot);
    snnl_loss<<<NROWS / 256, 256, 0, stream>>>(top, bot, out);
}

// Round 13
// 161.446 us; speedup vs baseline: 1.1956x; 1.1707x over previous
//
#include <hip/hip_runtime.h>

#define NROWS 8192
#define DDIM  1024

typedef float f32x4 __attribute__((ext_vector_type(4)));
typedef unsigned char uchar_t;

// async global->LDS, 16B per lane, linear LDS dest (wave-uniform base + lane*16)
#define GLD(gp, lp)                                                        \
    __builtin_amdgcn_global_load_lds(                                      \
        (const __attribute__((address_space(1))) void*)(gp),               \
        (__attribute__((address_space(3))) void*)(lp), 16, 0, 0)

// ============================================================================
// Kernel 1: row L2-normalize fp32 -> fp8 e4m3 (OCP, hw RNE pack).
// One WAVE per row, 4 rows/block. Also zeroes top/bot (and out).
// Unit-vector components are in [-1,1] -> no e4m3 saturation (max 448).
// ============================================================================
__global__ __launch_bounds__(256) void snnl_normalize(
    const float* __restrict__ x, uchar_t* __restrict__ xn,
    float* __restrict__ top, float* __restrict__ bot, float* __restrict__ out)
{
    const int tid  = (int)threadIdx.x;
    const int lane = tid & 63;
    const int row  = (int)blockIdx.x * 4 + (tid >> 6);
    if (lane == 0) { top[row] = 0.0f; bot[row] = 0.0f; }
    if (row == 0 && lane == 0) out[0] = 0.0f;

    const float4* xr = (const float4*)(x + (size_t)row * DDIM);
    float4 v[4];
#pragma unroll
    for (int st = 0; st < 4; ++st) v[st] = xr[st * 64 + lane];
    float ss = 0.0f;
#pragma unroll
    for (int st = 0; st < 4; ++st)
        ss += v[st].x * v[st].x + v[st].y * v[st].y
            + v[st].z * v[st].z + v[st].w * v[st].w;
#pragma unroll
    for (int m = 32; m >= 1; m >>= 1) ss += __shfl_xor(ss, m);
    const float inv = 1.0f / fmaxf(sqrtf(ss), 1e-8f);   // COS_EPS clamp
    unsigned int* xo = (unsigned int*)(xn + (size_t)row * DDIM);
#pragma unroll
    for (int st = 0; st < 4; ++st) {
        unsigned int u = 0;
        u = __builtin_amdgcn_cvt_pk_fp8_f32(v[st].x * inv, v[st].y * inv, u, false);
        u = __builtin_amdgcn_cvt_pk_fp8_f32(v[st].z * inv, v[st].w * inv, u, true);
        xo[st * 64 + lane] = u;                 // 4 fp8 bytes, coalesced
    }
}

// ============================================================================
// Kernel 2: fused sim-GEMM(fp8) + exp + masked row/col sums, upper triangle.
//  R7-verified structure UNCHANGED (128x128 tile, 4 waves 2x2, one tile per
//  block, XCD-coherent 8x8 superblock order, 2-barrier K-loop, fused
//  epilogue) — only the operand dtype changes to fp8 e4m3:
//   - BK = 128 fp8 = 128-BYTE rows -> LDS byte layout and the proven
//     (row&7)<<4 16B-chunk XOR swizzle are IDENTICAL to the bf16 kernel
//   - kt loop 16 -> 8 (barrier drains halve), staged bytes/tile 512->256KB
//     (R7-R12 counters: kernel is staging-bound; volume is the cost)
//   - mfma_f32_16x16x32_fp8_fp8 (same shape/rate/count as bf16; C/D layout
//     dtype-independent) ; frags via ds_read_b64, chunk-exact unswizzle,
//     2-way bank aliasing only (free)
//   - 4 blocks/CU: resident window = 2 superblocks = 4MB fp8 = L2-fit
// ============================================================================
__global__ __launch_bounds__(256, 4) void snnl_main(
    const uchar_t* __restrict__ xn, const int* __restrict__ y,
    const float* __restrict__ T,
    float* __restrict__ top, float* __restrict__ bot)
{
    // ---- tile index from XCD-coherent global order ----
    const int bid = (int)blockIdx.x;
    int rem = (bid & 7) * 260 + (bid >> 3);      // global tile index
    int p = 0, q = 0;
    {
        bool done = false;
        for (int qq = 0; qq < 8 && !done; ++qq) {
            for (int pp = 0; pp <= qq; ++pp) {
                const int c = (pp == qq) ? 36 : 64;
                if (rem < c) { p = pp; q = qq; done = true; break; }
                rem -= c;
            }
        }
    }
    int ti, tj;
    if (p == q) {                                // diag superblock: tri enum
        int t = rem; tj = 7;
        for (int cc = 0; cc < 8; ++cc) {
            if (t <= cc) { tj = cc; break; }
            t -= (cc + 1);
        }
        ti = t;
    } else {                                     // full superblock
        ti = rem & 7; tj = rem >> 3;
    }
    const int bi = p * 8 + ti;
    const int bj = q * 8 + tj;
    const bool strict = (bi < bj);               // off-diagonal tile

    __shared__ char smem[32768];                 // A tile 16KB | B tile 16KB
    __shared__ int  yrow_s[128];
    __shared__ int  ycol_s[128];

    const int tid  = (int)threadIdx.x;
    const int lane = tid & 63;
    const int w    = tid >> 6;
    const int wr   = w >> 1;              // wave row (0..1) -> 64 output rows
    const int wc   = w & 1;               // wave col (0..1) -> 64 output cols
    const int i0   = bi * 128;
    const int j0   = bj * 128;

    if (tid < 128) yrow_s[tid] = y[i0 + tid];
    else           ycol_s[tid - 128] = y[j0 + tid - 128];
    // first K-loop __syncthreads() covers these before any use

    const float invT = 1.0f / T[0];

    // --- staging: thread t stages 16B chunk (t&7) of row (t>>3) per 32-row
    //     group; source chunk pre-swizzled: src = (t&7) ^ ((t>>3)&7).
    //     LDS rows are 128B (128 fp8); involution: chunk ^= (row&7). ---
    const int  rr  = tid >> 3;                               // tile row % 32
    const int  scb = (((tid & 7) ^ (rr & 7)) << 4);          // source col byte
    const char* const xb = (const char*)xn;

    // --- fragment-read constants ---
    // frag (16x16x32 fp8): row = base + (lane&15); true k-bytes
    // [ks*32 + (lane>>4)*8, +8) -> chunk = (ks*2)|(g>>1), off = (g&1)*8;
    // stored chunk = chunk ^ (row&7) with row&7 == lane&7.
    const int g   = lane >> 4;                   // 0..3
    const int r7  = lane & 7;
    const int glo = (g & 1) << 3;                // byte offset within chunk
    const int gch = g >> 1;                      // chunk low bit
    int arow[4], brow[4];
#pragma unroll
    for (int mi = 0; mi < 4; ++mi) arow[mi] = (wr * 64 + mi * 16 + (lane & 15)) * 128;
#pragma unroll
    for (int ni = 0; ni < 4; ++ni) brow[ni] = 16384 + (wc * 64 + ni * 16 + (lane & 15)) * 128;

    const f32x4 zero4 = {0.0f, 0.0f, 0.0f, 0.0f};
    f32x4 acc[4][4];
#pragma unroll
    for (int mi = 0; mi < 4; ++mi)
#pragma unroll
        for (int ni = 0; ni < 4; ++ni) acc[mi][ni] = zero4;

    for (int kt = 0; kt < 8; ++kt) {             // 8 x BK=128 fp8
        const size_t kb = ((size_t)kt << 7) + (size_t)scb;
#pragma unroll
        for (int qq = 0; qq < 4; ++qq)
            GLD(xb + (((size_t)(i0 + qq * 32 + rr)) << 10) + kb,
                smem + (qq << 12) + (tid << 4));
#pragma unroll
        for (int qq = 0; qq < 4; ++qq)
            GLD(xb + (((size_t)(j0 + qq * 32 + rr)) << 10) + kb,
                smem + 16384 + (qq << 12) + (tid << 4));
        __syncthreads();   // compiler drains vmcnt before s_barrier

#pragma unroll
        for (int ks = 0; ks < 4; ++ks) {
            const int coff = ((((ks << 1) | gch) ^ r7) << 4) | glo;
            long af[4], bfr[4];
#pragma unroll
            for (int mi = 0; mi < 4; ++mi)
                af[mi] = *(const long*)(smem + arow[mi] + coff);
#pragma unroll
            for (int ni = 0; ni < 4; ++ni)
                bfr[ni] = *(const long*)(smem + brow[ni] + coff);
#pragma unroll
            for (int mi = 0; mi < 4; ++mi)
#pragma unroll
                for (int ni = 0; ni < 4; ++ni)
                    acc[mi][ni] = __builtin_amdgcn_mfma_f32_16x16x32_fp8_fp8(
                        af[mi], bfr[ni], acc[mi][ni], 0, 0, 0);
        }
        __syncthreads();
    }

    // ---- fused epilogue: f = exp((sim-1)/T), masked row AND col sums ----
    int yjv[4], jgv[4];
#pragma unroll
    for (int ni = 0; ni < 4; ++ni) {
        const int jloc = wc * 64 + ni * 16 + (lane & 15);
        yjv[ni] = ycol_s[jloc];
        jgv[ni] = j0 + jloc;
    }
    float ct[4], cb[4];                 // column accumulators (per ni)
#pragma unroll
    for (int ni = 0; ni < 4; ++ni) { ct[ni] = 0.0f; cb[ni] = 0.0f; }

#pragma unroll
    for (int mi = 0; mi < 4; ++mi) {
#pragma unroll
        for (int r = 0; r < 4; ++r) {
            const int il = wr * 64 + mi * 16 + ((lane >> 4) << 2) + r;
            const int ig = i0 + il;
            const int yi = yrow_s[il];
            float ba = 0.0f, ta = 0.0f;
#pragma unroll
            for (int ni = 0; ni < 4; ++ni) {
                const float fv = __expf((acc[mi][ni][r] - 1.0f) * invT);
                const bool  sm = (yi == yjv[ni]);
                const float bv = (ig != jgv[ni]) ? fv : 0.0f;  // off-diag mask
                const float tv = sm ? bv : 0.0f;               // same-label
                ba += bv;  ta += tv;
                cb[ni] += bv;  ct[ni] += tv;                   // mirror tile
            }
            // row reduce across the 16 lanes sharing this row, one atomic
            ta += __shfl_xor(ta, 1); ta += __shfl_xor(ta, 2);
            ta += __shfl_xor(ta, 4); ta += __shfl_xor(ta, 8);
            ba += __shfl_xor(ba, 1); ba += __shfl_xor(ba, 2);
            ba += __shfl_xor(ba, 4); ba += __shfl_xor(ba, 8);
            if ((lane & 15) == 0) {
                atomicAdd(&top[ig], ta);
                atomicAdd(&bot[ig], ba);
            }
        }
    }

    if (strict) {
        // col reduce: col = lane&15 fixed, sum the 4 lane-quarters
#pragma unroll
        for (int ni = 0; ni < 4; ++ni) {
            float tv = ct[ni], bv = cb[ni];
            tv += __shfl_xor(tv, 16); tv += __shfl_xor(tv, 32);
            bv += __shfl_xor(bv, 16); bv += __shfl_xor(bv, 32);
            if (lane < 16) {
                atomicAdd(&top[jgv[ni]], tv);
                atomicAdd(&bot[jgv[ni]], bv);
            }
        }
    }
}

// ============================================================================
// Kernel 3: loss = -mean(log((top+1e-9)/bot)); out pre-zeroed by normalize.
// ============================================================================
__global__ __launch_bounds__(256) void snnl_loss(
    const float* __restrict__ top, const float* __restrict__ bot,
    float* __restrict__ out)
{
    const int tid = (int)threadIdx.x;
    const int i   = (int)blockIdx.x * 256 + tid;
    float s = __logf((top[i] + 1e-9f) / bot[i]);
#pragma unroll
    for (int m = 32; m >= 1; m >>= 1) s += __shfl_xor(s, m);
    __shared__ float w4[4];
    if ((tid & 63) == 0) w4[tid >> 6] = s;
    __syncthreads();
    if (tid == 0)
        atomicAdd(out, -(w4[0] + w4[1] + w4[2] + w4[3]) * (1.0f / (float)NROWS));
}

// ============================================================================
extern "C" void kernel_launch(void* const* d_in, const int* in_sizes, int n_in,
                              void* d_out, int out_size, void* d_ws, size_t ws_size,
                              hipStream_t stream)
{
    const float* x = (const float*)d_in[0];
    const int*   y = (const int*)d_in[1];
    const float* T = (const float*)d_in[2];
    float* out = (float*)d_out;

    char* ws = (char*)d_ws;
    uchar_t* xn  = (uchar_t*)ws;                               // 8 MiB fp8 Xn
    float*   top = (float*)(ws + (size_t)8 * 1024 * 1024);     // 32 KiB
    float*   bot = top + NROWS;                                // 32 KiB

    snnl_normalize<<<NROWS / 4, 256, 0, stream>>>(x, xn, top, bot, out);
    snnl_main<<<2080, 256, 0, stream>>>(xn, y, T, top, bot);
    snnl_loss<<<NROWS / 256, 256, 0, stream>>>(top, bot, out);
}